// Round 3
// baseline (383.307 us; speedup 1.0000x reference)
//
#include <hip/hip_runtime.h>

// Problem constants
#define B_  16
#define S_  1024
#define IN_ 1024
#define H_  1024
#define N1  (2*H_)          // 2048 output cols of GEMM1
#define M1  (B_*S_)         // 16384 rows of GEMM1
#define K1  IN_             // 1024
#define WN  (N1*IN_)        //  2,097,152 elems of W

// 256x256x64 8-wave tile, double-buffered split-K LDS, counted-vmcnt pipeline
#define BM  256
#define BN  256
#define BK  64
#define CP  257             // epilogue transpose LDS stride (odd -> conflict-free)

// LDS layout (shorts): per tile buffer = 32768 shorts (64 KiB):
//   A[kh=0][256][32] | A[kh=1][256][32] | B[kh=0][256][32] | B[kh=1][256][32]
#define USZ  8192
#define ASZ  16384
#define TBUF 32768

typedef __attribute__((ext_vector_type(8))) short  short8;   // 8 bf16 (MFMA A/B frag)
typedef __attribute__((ext_vector_type(4))) float  floatx4;  // MFMA C/D frag

// fp32 -> bf16 round-to-nearest-even (scalar, epilogue/convert use)
__device__ __forceinline__ unsigned short f2bf(float f) {
    unsigned int u = __float_as_uint(f);
    u += 0x7fffu + ((u >> 16) & 1u);
    return (unsigned short)(u >> 16);
}

// async global->LDS, 16 B per lane; LDS dst is wave-uniform base + lane*16
#define GLDS16(gp, lp) __builtin_amdgcn_global_load_lds(                      \
    (const __attribute__((address_space(1))) void*)(gp),                      \
    (__attribute__((address_space(3))) void*)(lp), 16, 0, 0)

#define WAITVM(N) { asm volatile("s_waitcnt vmcnt(" #N ")" ::: "memory");     \
                    __builtin_amdgcn_s_barrier();                             \
                    __builtin_amdgcn_sched_barrier(0); }

// ---------------------------------------------------------------------------
// convert W only: fp32 -> bf16 (x conversion is fused into gemm1).
// ---------------------------------------------------------------------------
__global__ __launch_bounds__(256) void convert_w(
    const float* __restrict__ W, unsigned short* __restrict__ Wb)
{
    size_t i = ((size_t)blockIdx.x * 256 + threadIdx.x) * 8;
    float4 a = *(const float4*)(W + i);
    float4 b = *(const float4*)(W + i + 4);
    ushort4 p = { f2bf(a.x), f2bf(a.y), f2bf(a.z), f2bf(a.w) };
    ushort4 q = { f2bf(b.x), f2bf(b.y), f2bf(b.z), f2bf(b.w) };
    *(ushort4*)(Wb + i)     = p;
    *(ushort4*)(Wb + i + 4) = q;
}

// ---------------------------------------------------------------------------
// gemm1 A-path helpers: f32 global -> regs -> cvt_pk -> swizzled LDS (T14).
// Chunk map identical to the glds path: chunk e=(wave*2+h)*64+lane,
// row=e>>2, phys p=e&3 holds logical c=p^(row&3); LDS linear at e*16 B.
// ---------------------------------------------------------------------------
__device__ __forceinline__ void a_issue(const float* Ag, int koff,
                                        float4 (&s)[2][2], int wave, int lane)
{
#pragma unroll
    for (int h = 0; h < 2; ++h) {
        int e   = (wave * 2 + h) * 64 + lane;
        int row = e >> 2, pp = e & 3;
        int c   = pp ^ (row & 3);
        const float* src = Ag + (size_t)row * 1024 + koff + c * 8;
        s[h][0] = *(const float4*)(src);
        s[h][1] = *(const float4*)(src + 4);
    }
}

__device__ __forceinline__ void a_write(unsigned short* ubase,
                                        const float4 (&s)[2][2], int wave, int lane)
{
#pragma unroll
    for (int h = 0; h < 2; ++h) {
        unsigned int o0, o1, o2, o3;
        asm("v_cvt_pk_bf16_f32 %0, %1, %2" : "=v"(o0) : "v"(s[h][0].x), "v"(s[h][0].y));
        asm("v_cvt_pk_bf16_f32 %0, %1, %2" : "=v"(o1) : "v"(s[h][0].z), "v"(s[h][0].w));
        asm("v_cvt_pk_bf16_f32 %0, %1, %2" : "=v"(o2) : "v"(s[h][1].x), "v"(s[h][1].y));
        asm("v_cvt_pk_bf16_f32 %0, %1, %2" : "=v"(o3) : "v"(s[h][1].z), "v"(s[h][1].w));
        uint4 w = { o0, o1, o2, o3 };
        *(uint4*)(ubase + (wave * 2 + h) * 512 + lane * 8) = w;   // ds_write_b128
    }
}

__device__ __forceinline__ void b_stage(const unsigned short* Bg,
                                        unsigned short* buf, int kh, int koff,
                                        int wave, int lane)
{
#pragma unroll
    for (int h = 0; h < 2; ++h) {
        int e   = (wave * 2 + h) * 64 + lane;
        int row = e >> 2, pp = e & 3;
        int c   = pp ^ (row & 3);
        GLDS16(Bg + (size_t)row * 1024 + koff + c * 8,
               buf + ASZ + kh * USZ + (wave * 2 + h) * 512);
    }
}

// One pipeline phase of gemm1. Each phase issues exactly 6 VMEM ops in the
// main loop (4 A-dwordx4 + 2 B-glds) -> barrier waits vmcnt(6): drains
// phase p-2 fully (A regs for cvt + current B unit), keeps p-1's 6 in flight.
#define PHASE(bc_, bn_, kh_, SET, W_, I_, BS_, kA_, kB_, VM_)                 \
{                                                                             \
    asm volatile("s_waitcnt vmcnt(" VM_ ") lgkmcnt(0)" ::: "memory");         \
    __builtin_amdgcn_s_barrier();                                             \
    __builtin_amdgcn_sched_barrier(0);                                        \
    const unsigned short* cA = (bc_) + (kh_) * USZ;                           \
    const unsigned short* cB = (bc_) + ASZ + (kh_) * USZ;                     \
    short8 bfr[4], af0[4], af1[4];                                            \
    _Pragma("unroll") for (int j = 0; j < 4; ++j)                             \
        bfr[j] = *(const short8*)(cB + (wnw + j * 16 + r) * 32 + sw);         \
    _Pragma("unroll") for (int i = 0; i < 4; ++i)                             \
        af0[i] = *(const short8*)(cA + (wmw + i * 16 + r) * 32 + sw);         \
    _Pragma("unroll") for (int i = 0; i < 4; ++i)                             \
        af1[i] = *(const short8*)(cA + (wmw + (4 + i) * 16 + r) * 32 + sw);   \
    if (W_) a_write((bn_) + (kh_) * USZ, SET, wave, lane);                    \
    if (I_) a_issue(Ag, (kA_), SET, wave, lane);                              \
    if (BS_) b_stage(Bg, (bn_), (kh_), (kB_), wave, lane);                    \
    __builtin_amdgcn_s_setprio(1);                                            \
    _Pragma("unroll") for (int i = 0; i < 4; ++i)                             \
        _Pragma("unroll") for (int j = 0; j < 4; ++j)                         \
            acc[i][j] = __builtin_amdgcn_mfma_f32_16x16x32_bf16(              \
                af0[i], bfr[j], acc[i][j], 0, 0, 0);                          \
    _Pragma("unroll") for (int i = 0; i < 4; ++i)                             \
        _Pragma("unroll") for (int j = 0; j < 4; ++j)                         \
            acc[4 + i][j] = __builtin_amdgcn_mfma_f32_16x16x32_bf16(          \
                af1[i], bfr[j], acc[4 + i][j], 0, 0, 0);                      \
    __builtin_amdgcn_s_setprio(0);                                            \
    __builtin_amdgcn_sched_barrier(0);                                        \
}

// ---------------------------------------------------------------------------
// GEMM1: C[m,n] = sum_k x[m,k]*Wb[n,k], x read as f32 and converted in-flight.
// relu -> fp32 keys/vals to d_out + bf16 transposed keysT/valsT to ws.
// 512 blocks; XCD x owns m-stripe [8x,8x+8) x 8 n-tiles.
// ---------------------------------------------------------------------------
__global__ __launch_bounds__(512, 2) void gemm1_kernel(
    const float* __restrict__ x, const unsigned short* __restrict__ Wb,
    float* __restrict__ out,
    unsigned short* __restrict__ kT, unsigned short* __restrict__ vT)
{
    __shared__ unsigned short lds[65536];         // 128 KiB

    const int tid  = threadIdx.x;
    const int wave = tid >> 6, lane = tid & 63;
    const int quad = lane >> 4, r = lane & 15;
    const int wmw  = (wave >> 2) * 128;
    const int wnw  = (wave & 3) * 64;
    const int sw   = (quad ^ (r & 3)) * 8;

    const int L   = blockIdx.x;
    const int xcd = L & 7, s = L >> 3;            // s: 0..63
    const int mt  = xcd * 8 + (s >> 3);           // 0..63
    const int nt  = s & 7;                        // 0..7
    const int m0  = mt * BM, n0 = nt * BN;

    const float*          Ag = x  + (size_t)m0 * K1;
    const unsigned short* Bg = Wb + (size_t)n0 * K1;

    floatx4 acc[8][4] = {};
    float4  s0[2][2], s1[2][2];

    // Prologue: units 0,1 A direct (load+cvt+write); prime pipeline so that
    // at barrier 0 the outstanding queue is [A2(4),B0(2),A3(4),B1(2)] —
    // exactly the steady-state pattern.
    a_issue(Ag, 0 * 32, s0, wave, lane);
    a_issue(Ag, 1 * 32, s1, wave, lane);
    asm volatile("s_waitcnt vmcnt(4)" ::: "memory");
    a_write(lds + 0 * USZ, s0, wave, lane);       // unit 0 (buf0, kh0)
    asm volatile("s_waitcnt vmcnt(0)" ::: "memory");
    a_write(lds + 1 * USZ, s1, wave, lane);       // unit 1 (buf0, kh1)
    a_issue(Ag, 2 * 32, s0, wave, lane);          // unit 2 -> cvt at phase 0
    b_stage(Bg, lds, 0, 0 * 32, wave, lane);      // B unit 0
    a_issue(Ag, 3 * 32, s1, wave, lane);          // unit 3 -> cvt at phase 1
    b_stage(Bg, lds, 1, 1 * 32, wave, lane);      // B unit 1

    // Main loop: phases p=2t, 2t+1 for t=0..13 (units 0..27), all vmcnt(6)
    for (int t = 0; t < 14; ++t) {
        unsigned short* bc = lds + (t & 1) * TBUF;
        unsigned short* bn = lds + ((t + 1) & 1) * TBUF;
        PHASE(bc, bn, 0, s0, 1, 1, 1, (2 * t + 4) * 32, (2 * t + 2) * 32, "6")
        PHASE(bc, bn, 1, s1, 1, 1, 1, (2 * t + 5) * 32, (2 * t + 3) * 32, "6")
    }
    {   // t=14: phases 28,29 — write units 30,31; no A issue; stage B 30,31
        unsigned short* bc = lds;                 // 14&1 = 0
        unsigned short* bn = lds + TBUF;
        PHASE(bc, bn, 0, s0, 1, 0, 1, 0, 30 * 32, "6")
        PHASE(bc, bn, 1, s1, 1, 0, 1, 0, 31 * 32, "2")
    }
    {   // t=15: phases 30,31 — consume only, drain
        unsigned short* bc = lds + TBUF;
        PHASE(bc, bc, 0, s0, 0, 0, 0, 0, 0, "2")
        PHASE(bc, bc, 1, s1, 0, 0, 0, 0, 0, "0")
    }
    __syncthreads();                              // LDS reusable by epilogue

    const bool isKeys = (nt < 4);
    float* outKV    = out + (isKeys ? (size_t)M1 * H_ : (size_t)2 * M1 * H_);
    const int ncol0 = isKeys ? n0 : (n0 - 1024);

    // fp32 relu writes (each wave its own 128x64 region)
#pragma unroll
    for (int f = 0; f < 8; ++f)
#pragma unroll
        for (int j = 0; j < 4; ++j)
#pragma unroll
            for (int d = 0; d < 4; ++d) {
                int row_l = wmw + f * 16 + quad * 4 + d;
                int col_l = wnw + j * 16 + r;
                outKV[(size_t)(m0 + row_l) * H_ + ncol0 + col_l] =
                    fmaxf(acc[f][j][d], 0.0f);
            }

    // bf16 transposed writes via LDS, 2 chunks of 128 rows
    unsigned short* wsT = isKeys ? kT : vT;
    const int b  = m0 >> 10;
    const int sq = m0 & 1023;
    unsigned short* dstB = wsT + (size_t)b * H_ * S_ + (size_t)ncol0 * S_ + sq;

#pragma unroll
    for (int ch = 0; ch < 2; ++ch) {
        if ((wave >> 2) == ch) {
#pragma unroll
            for (int f = 0; f < 8; ++f)
#pragma unroll
                for (int j = 0; j < 4; ++j)
#pragma unroll
                    for (int d = 0; d < 4; ++d) {
                        int lrow = f * 16 + quad * 4 + d;    // 0..127
                        int col  = wnw + j * 16 + r;         // 0..255
                        lds[lrow * CP + col] = f2bf(fmaxf(acc[f][j][d], 0.0f));
                    }
        }
        __syncthreads();
#pragma unroll
        for (int it = 0; it < 16; ++it) {
            int o   = it * 512 + tid;
            int n_l = o >> 5;                     // 0..255
            int m4  = (o & 31) * 4;               // 0..124
            ushort4 v;
            v.x = lds[(m4 + 0) * CP + n_l];
            v.y = lds[(m4 + 1) * CP + n_l];
            v.z = lds[(m4 + 2) * CP + n_l];
            v.w = lds[(m4 + 3) * CP + n_l];
            *(ushort4*)(dstB + (size_t)n_l * S_ + ch * 128 + m4) = v;
        }
        __syncthreads();
    }
}

// ---------------------------------------------------------------------------
// GEMM2 (unchanged from round 2): mem[b][m,n] = sum_t kT[b][m,t]*vT[b][n,t]
// bf16 glds staging both operands, counted-vmcnt double buffer.
// ---------------------------------------------------------------------------
__device__ __forceinline__ void stage_u(
    const unsigned short* Ag, const unsigned short* Bg,
    unsigned short* buf, int op, int kh, int kt, int wave, int lane)
{
    const unsigned short* src = op ? Bg : Ag;
    unsigned short* dst = buf + op * ASZ + kh * USZ;
#pragma unroll
    for (int h = 0; h < 2; ++h) {
        int e   = (wave * 2 + h) * 64 + lane;
        int row = e >> 2, p = e & 3;
        int c   = p ^ (row & 3);
        GLDS16(src + (size_t)row * 1024 + kt + kh * 32 + c * 8,
               dst + (wave * 2 + h) * 512);
    }
}

__device__ __forceinline__ void half_tile(
    const unsigned short* bufc, floatx4 (&acc)[8][4], int kc,
    const unsigned short* Ag, const unsigned short* Bg,
    unsigned short* bufn, int ktn, bool st,
    int wave, int lane, int wmw, int wnw, int quad, int r)
{
    const unsigned short* cA = bufc + kc * USZ;
    const unsigned short* cB = bufc + ASZ + kc * USZ;
    const int sw = (quad ^ (r & 3)) * 8;
    short8 bfr[4];
#pragma unroll
    for (int j = 0; j < 4; ++j)
        bfr[j] = *(const short8*)(cB + (wnw + j * 16 + r) * 32 + sw);
#pragma unroll
    for (int mh = 0; mh < 2; ++mh) {
        short8 af[4];
#pragma unroll
        for (int i = 0; i < 4; ++i)
            af[i] = *(const short8*)(cA + (wmw + (mh * 4 + i) * 16 + r) * 32 + sw);
        if (st) stage_u(Ag, Bg, bufn, mh, kc, ktn, wave, lane);
        __builtin_amdgcn_s_setprio(1);
#pragma unroll
        for (int i = 0; i < 4; ++i)
#pragma unroll
            for (int j = 0; j < 4; ++j)
                acc[mh * 4 + i][j] = __builtin_amdgcn_mfma_f32_16x16x32_bf16(
                    af[i], bfr[j], acc[mh * 4 + i][j], 0, 0, 0);
        __builtin_amdgcn_s_setprio(0);
    }
}

__device__ __forceinline__ void gemm_core(
    const unsigned short* Ag, const unsigned short* Bg,
    unsigned short* lds, floatx4 (&acc)[8][4], int wave, int lane)
{
    const int quad = lane >> 4, r = lane & 15;
    const int wmw  = (wave >> 2) * 128;
    const int wnw  = (wave & 3) * 64;

    stage_u(Ag, Bg, lds, 0, 0, 0, wave, lane);
    stage_u(Ag, Bg, lds, 1, 0, 0, wave, lane);
    stage_u(Ag, Bg, lds, 0, 1, 0, wave, lane);
    stage_u(Ag, Bg, lds, 1, 1, 0, wave, lane);

    for (int t = 0; t < 15; ++t) {
        unsigned short* bufc = lds + (t & 1) * TBUF;
        unsigned short* bufn = lds + ((t + 1) & 1) * TBUF;
        const int ktn = (t + 1) * BK;
        WAITVM(4)
        half_tile(bufc, acc, 0, Ag, Bg, bufn, ktn, true, wave, lane, wmw, wnw, quad, r);
        WAITVM(4)
        half_tile(bufc, acc, 1, Ag, Bg, bufn, ktn, true, wave, lane, wmw, wnw, quad, r);
    }
    {
        unsigned short* bufc = lds + TBUF;
        WAITVM(4)
        half_tile(bufc, acc, 0, Ag, Bg, bufc, 0, false, wave, lane, wmw, wnw, quad, r);
        WAITVM(0)
        half_tile(bufc, acc, 1, Ag, Bg, bufc, 0, false, wave, lane, wmw, wnw, quad, r);
    }
    __syncthreads();
}

__global__ __launch_bounds__(512, 2) void gemm2_kernel(
    const unsigned short* __restrict__ kT, const unsigned short* __restrict__ vT,
    float* __restrict__ mem)
{
    __shared__ unsigned short lds[65536];         // 128 KiB

    const int tid  = threadIdx.x;
    const int wave = tid >> 6, lane = tid & 63;
    const int quad = lane >> 4, r = lane & 15;
    const int wmw  = (wave >> 2) * 128;
    const int wnw  = (wave & 3) * 64;

    const int L   = blockIdx.x;
    const int xcd = L & 7, s = L >> 3;            // s: 0..31
    const int b   = xcd * 2 + (s >> 4);           // batch
    const int tt  = s & 15;
    const int m0  = (tt >> 2) * BM;
    const int n0  = (tt & 3) * BN;

    const unsigned short* Ag = kT + (size_t)b * H_ * S_ + (size_t)m0 * S_;
    const unsigned short* Bg = vT + (size_t)b * H_ * S_ + (size_t)n0 * S_;

    floatx4 acc[8][4] = {};
    gemm_core(Ag, Bg, lds, acc, wave, lane);

    float* outb = mem + (size_t)b * H_ * H_;
#pragma unroll
    for (int f = 0; f < 8; ++f)
#pragma unroll
        for (int j = 0; j < 4; ++j)
#pragma unroll
            for (int d = 0; d < 4; ++d) {
                int row_l = wmw + f * 16 + quad * 4 + d;
                int col_l = wnw + j * 16 + r;
                outb[(size_t)(m0 + row_l) * H_ + n0 + col_l] = acc[f][j][d];
            }
}

extern "C" void kernel_launch(void* const* d_in, const int* in_sizes, int n_in,
                              void* d_out, int out_size, void* d_ws, size_t ws_size,
                              hipStream_t stream) {
    const float* x = (const float*)d_in[0];   // [16,1024,1024] f32
    const float* W = (const float*)d_in[1];   // [2048,1024] f32
    float* out = (float*)d_out;               // mem(16M) | keys(16M) | vals(16M) f32

    // Wb bf16 stashed in d_out's mem region (not written until gemm2)
    unsigned short* Wb = (unsigned short*)d_out;            // 4.2 MB

    // ws: keysT/valsT bf16 [B][H][S] (64 MB)
    unsigned short* kT = (unsigned short*)d_ws;
    unsigned short* vT = kT + (size_t)B_ * H_ * S_;

    convert_w<<<dim3(WN / 2048), dim3(256), 0, stream>>>(W, Wb);

    gemm1_kernel<<<dim3(512), dim3(512), 0, stream>>>(x, Wb, out, kT, vT);

    gemm2_kernel<<<dim3(256), dim3(512), 0, stream>>>(kT, vT, out);
}

// Round 4
// 352.677 us; speedup vs baseline: 1.0868x; 1.0868x over previous
//
#include <hip/hip_runtime.h>

// Problem constants
#define B_  16
#define S_  1024
#define IN_ 1024
#define H_  1024
#define N1  (2*H_)          // 2048 output cols of GEMM1
#define M1  (B_*S_)         // 16384 rows of GEMM1
#define K1  IN_             // 1024
#define XN  (M1*IN_)        // 16,777,216 elems of x
#define WN  (N1*IN_)        //  2,097,152 elems of W

// gemm1: 256x256x64 8-wave tile, double-buffered split-K LDS, counted vmcnt
#define BM  256
#define BN  256
#define BK  64
#define CP  257             // epilogue transpose LDS stride (odd -> conflict-free)

// gemm1 LDS layout (shorts): per tile buffer = 32768 shorts (64 KiB):
//   A[kh=0][256][32] | A[kh=1][256][32] | B[kh=0][256][32] | B[kh=1][256][32]
#define USZ  8192
#define ASZ  16384
#define TBUF 32768

typedef __attribute__((ext_vector_type(8))) short  short8;   // 8 bf16 (MFMA A/B frag)
typedef __attribute__((ext_vector_type(4))) float  floatx4;  // MFMA C/D frag

// fp32 -> bf16 round-to-nearest-even
__device__ __forceinline__ unsigned short f2bf(float f) {
    unsigned int u = __float_as_uint(f);
    u += 0x7fffu + ((u >> 16) & 1u);
    return (unsigned short)(u >> 16);
}

// async global->LDS, 16 B per lane; LDS dst is wave-uniform base + lane*16
#define GLDS16(gp, lp) __builtin_amdgcn_global_load_lds(                      \
    (const __attribute__((address_space(1))) void*)(gp),                      \
    (__attribute__((address_space(3))) void*)(lp), 16, 0, 0)

#define WAITVM(N) { asm volatile("s_waitcnt vmcnt(" #N ")" ::: "memory");     \
                    __builtin_amdgcn_s_barrier();                             \
                    __builtin_amdgcn_sched_barrier(0); }

// ---------------------------------------------------------------------------
// convert: fp32 -> bf16 for x and W (memory-bound).
// ---------------------------------------------------------------------------
__global__ __launch_bounds__(256) void convert_kernel(
    const float* __restrict__ x, const float* __restrict__ W,
    unsigned short* __restrict__ xb, unsigned short* __restrict__ Wb)
{
    size_t i = ((size_t)blockIdx.x * 256 + threadIdx.x) * 8;
    const float* src;
    unsigned short* dst;
    if (i < (size_t)XN) { src = x + i; dst = xb + i; }
    else                { src = W + (i - XN); dst = Wb + (i - XN); }
    float4 a = *(const float4*)(src);
    float4 b = *(const float4*)(src + 4);
    ushort4 p = { f2bf(a.x), f2bf(a.y), f2bf(a.z), f2bf(a.w) };
    ushort4 q = { f2bf(b.x), f2bf(b.y), f2bf(b.z), f2bf(b.w) };
    *(ushort4*)(dst)     = p;
    *(ushort4*)(dst + 4) = q;
}

// ---------------------------------------------------------------------------
// gemm1 staging: one 16 KiB unit (op: 0=A 1=B, kh: k-half) at kt into buf.
// Swizzle on GLOBAL source: phys chunk p at row holds logical c = p^(row&3).
// Reader slot = (4r + q^(r&3)) mod 8 -> uniform 8 lanes/slot = b128 floor.
// ---------------------------------------------------------------------------
__device__ __forceinline__ void stage_u(
    const unsigned short* Ag, const unsigned short* Bg,
    unsigned short* buf, int op, int kh, int kt, int wave, int lane)
{
    const unsigned short* src = op ? Bg : Ag;
    unsigned short* dst = buf + op * ASZ + kh * USZ;
#pragma unroll
    for (int h = 0; h < 2; ++h) {
        int e   = (wave * 2 + h) * 64 + lane;     // chunk id 0..1023 in unit
        int row = e >> 2, p = e & 3;
        int c   = p ^ (row & 3);
        GLDS16(src + (size_t)row * 1024 + kt + kh * 32 + c * 8,
               dst + (wave * 2 + h) * 512);
    }
}

// one k-half of one K-tile: 4 B-frags, 2x{4 A-frags + optional stage + 16 MFMA}
__device__ __forceinline__ void half_tile(
    const unsigned short* bufc, floatx4 (&acc)[8][4], int kc,
    const unsigned short* Ag, const unsigned short* Bg,
    unsigned short* bufn, int ktn, bool st,
    int wave, int lane, int wmw, int wnw, int quad, int r)
{
    const unsigned short* cA = bufc + kc * USZ;
    const unsigned short* cB = bufc + ASZ + kc * USZ;
    const int sw = (quad ^ (r & 3)) * 8;          // phys chunk slot (shorts)
    short8 bfr[4];
#pragma unroll
    for (int j = 0; j < 4; ++j)
        bfr[j] = *(const short8*)(cB + (wnw + j * 16 + r) * 32 + sw);
#pragma unroll
    for (int mh = 0; mh < 2; ++mh) {
        short8 af[4];
#pragma unroll
        for (int i = 0; i < 4; ++i)
            af[i] = *(const short8*)(cA + (wmw + (mh * 4 + i) * 16 + r) * 32 + sw);
        if (st) stage_u(Ag, Bg, bufn, mh, kc, ktn, wave, lane);
        __builtin_amdgcn_s_setprio(1);
#pragma unroll
        for (int i = 0; i < 4; ++i)
#pragma unroll
            for (int j = 0; j < 4; ++j)
                acc[mh * 4 + i][j] = __builtin_amdgcn_mfma_f32_16x16x32_bf16(
                    af[i], bfr[j], acc[mh * 4 + i][j], 0, 0, 0);
        __builtin_amdgcn_s_setprio(0);
    }
}

// gemm1 K-loop: 16 K-tiles, 2x64 KiB double buffer, counted-vmcnt pipeline.
__device__ __forceinline__ void gemm_core(
    const unsigned short* Ag, const unsigned short* Bg,
    unsigned short* lds, floatx4 (&acc)[8][4], int wave, int lane)
{
    const int quad = lane >> 4, r = lane & 15;
    const int wmw  = (wave >> 2) * 128;           // 2 wave-rows x 4 wave-cols
    const int wnw  = (wave & 3) * 64;

    stage_u(Ag, Bg, lds, 0, 0, 0, wave, lane);
    stage_u(Ag, Bg, lds, 1, 0, 0, wave, lane);
    stage_u(Ag, Bg, lds, 0, 1, 0, wave, lane);
    stage_u(Ag, Bg, lds, 1, 1, 0, wave, lane);

    for (int t = 0; t < 15; ++t) {
        unsigned short* bufc = lds + (t & 1) * TBUF;
        unsigned short* bufn = lds + ((t + 1) & 1) * TBUF;
        const int ktn = (t + 1) * BK;
        WAITVM(4)   // kh0(t) landed; kh1(t) may fly
        half_tile(bufc, acc, 0, Ag, Bg, bufn, ktn, true, wave, lane, wmw, wnw, quad, r);
        WAITVM(4)   // kh1(t) landed; kh0(t+1) may fly
        half_tile(bufc, acc, 1, Ag, Bg, bufn, ktn, true, wave, lane, wmw, wnw, quad, r);
    }
    {   // peeled tile 15: no staging, final drain
        unsigned short* bufc = lds + TBUF;
        WAITVM(4)
        half_tile(bufc, acc, 0, Ag, Bg, bufc, 0, false, wave, lane, wmw, wnw, quad, r);
        WAITVM(0)
        half_tile(bufc, acc, 1, Ag, Bg, bufc, 0, false, wave, lane, wmw, wnw, quad, r);
    }
    __syncthreads();                              // LDS reusable by epilogue
}

// ---------------------------------------------------------------------------
// GEMM1: C[m,n] = sum_k xb[m,k]*Wb[n,k]; relu -> fp32 keys/vals to d_out and
// bf16 transposed keysT/valsT to ws. 512 blocks; XCD x owns m-stripe
// [8x,8x+8) x all 8 n-tiles.
// ---------------------------------------------------------------------------
__global__ __launch_bounds__(512, 2) void gemm1_kernel(
    const unsigned short* __restrict__ xb, const unsigned short* __restrict__ Wb,
    float* __restrict__ out,
    unsigned short* __restrict__ kT, unsigned short* __restrict__ vT)
{
    __shared__ unsigned short lds[65536];         // 128 KiB

    const int tid  = threadIdx.x;
    const int wave = tid >> 6, lane = tid & 63;
    const int quad = lane >> 4, r = lane & 15;
    const int wmw  = (wave >> 2) * 128;
    const int wnw  = (wave & 3) * 64;

    const int L   = blockIdx.x;
    const int xcd = L & 7, s = L >> 3;            // s: 0..63
    const int mt  = xcd * 8 + (s >> 3);           // 0..63
    const int nt  = s & 7;                        // 0..7
    const int m0  = mt * BM, n0 = nt * BN;

    const unsigned short* Ag = xb + (size_t)m0 * K1;
    const unsigned short* Bg = Wb + (size_t)n0 * K1;

    floatx4 acc[8][4] = {};
    gemm_core(Ag, Bg, lds, acc, wave, lane);

    const bool isKeys = (nt < 4);
    float* outKV    = out + (isKeys ? (size_t)M1 * H_ : (size_t)2 * M1 * H_);
    const int ncol0 = isKeys ? n0 : (n0 - 1024);

    // fp32 relu writes (each wave its own 128x64 region)
#pragma unroll
    for (int f = 0; f < 8; ++f)
#pragma unroll
        for (int j = 0; j < 4; ++j)
#pragma unroll
            for (int d = 0; d < 4; ++d) {
                int row_l = wmw + f * 16 + quad * 4 + d;
                int col_l = wnw + j * 16 + r;
                outKV[(size_t)(m0 + row_l) * H_ + ncol0 + col_l] =
                    fmaxf(acc[f][j][d], 0.0f);
            }

    // bf16 transposed writes via LDS, 2 chunks of 128 rows (CP=257)
    unsigned short* wsT = isKeys ? kT : vT;
    const int b  = m0 >> 10;
    const int s0 = m0 & 1023;
    unsigned short* dstB = wsT + (size_t)b * H_ * S_ + (size_t)ncol0 * S_ + s0;

#pragma unroll
    for (int ch = 0; ch < 2; ++ch) {
        if ((wave >> 2) == ch) {
#pragma unroll
            for (int f = 0; f < 8; ++f)
#pragma unroll
                for (int j = 0; j < 4; ++j)
#pragma unroll
                    for (int d = 0; d < 4; ++d) {
                        int lrow = f * 16 + quad * 4 + d;    // 0..127
                        int col  = wnw + j * 16 + r;         // 0..255
                        lds[lrow * CP + col] = f2bf(fmaxf(acc[f][j][d], 0.0f));
                    }
        }
        __syncthreads();
#pragma unroll
        for (int it = 0; it < 16; ++it) {
            int o   = it * 512 + tid;
            int n_l = o >> 5;                     // 0..255
            int m4  = (o & 31) * 4;               // 0..124
            ushort4 v;
            v.x = lds[(m4 + 0) * CP + n_l];
            v.y = lds[(m4 + 1) * CP + n_l];
            v.z = lds[(m4 + 2) * CP + n_l];
            v.w = lds[(m4 + 3) * CP + n_l];
            *(ushort4*)(dstB + (size_t)n_l * S_ + ch * 128 + m4) = v;
        }
        __syncthreads();
    }
}

// ---------------------------------------------------------------------------
// GEMM2 (batched): mem[b][m,n] = sum_t kT[b][m,t]*vT[b][n,t].
// m97-class structure: 128x128 tile, 256 threads (4 waves, 2x2 of 64x64),
// 32 KiB single-buffered LDS -> ~4 independent blocks/CU whose staggered
// phases hide each other's barrier drains (m114 overlap) — replaces the
// 1-block/CU barrier-locked 256^2 version (no co-resident work to hide
// stalls). 1024 blocks; XCD x owns batches {2x,2x+1} (4 MB fits its L2).
// LDS: A[kh][128][32] | B[kh][128][32] (same split-chunk swizzle as gemm1).
// ---------------------------------------------------------------------------
__global__ __launch_bounds__(256, 4) void gemm2_kernel(
    const unsigned short* __restrict__ kT, const unsigned short* __restrict__ vT,
    float* __restrict__ mem)
{
    __shared__ unsigned short lds[16384];         // 32 KiB

    const int tid  = threadIdx.x;
    const int wave = tid >> 6, lane = tid & 63;
    const int quad = lane >> 4, r = lane & 15;
    const int wm   = (wave >> 1) * 64;
    const int wn   = (wave & 1) * 64;
    const int sw   = (quad ^ (r & 3)) * 8;

    const int L   = blockIdx.x;
    const int xcd = L & 7, s = L >> 3;            // s: 0..127
    const int b   = xcd * 2 + (s >> 6);           // batch 0..15
    const int t   = s & 63;
    const int m0  = (t >> 3) * 128;
    const int n0  = (t & 7) * 128;

    const unsigned short* Ag = kT + (size_t)b * H_ * S_ + (size_t)m0 * S_;
    const unsigned short* Bg = vT + (size_t)b * H_ * S_ + (size_t)n0 * S_;

    floatx4 acc[4][4] = {};

    for (int kt = 0; kt < S_; kt += 64) {
        __syncthreads();                          // prev tile's reads done
#pragma unroll
        for (int h = 0; h < 4; ++h) {
            int e   = (wave * 4 + h) * 64 + lane; // chunk 0..1023
            int kh  = e >> 9, i2 = e & 511;
            int row = i2 >> 2, p = i2 & 3;
            int c   = p ^ (row & 3);
            size_t goff = (size_t)row * 1024 + kt + kh * 32 + c * 8;
            GLDS16(Ag + goff, lds + (size_t)e * 8);
            GLDS16(Bg + goff, lds + 8192 + (size_t)e * 8);
        }
        __syncthreads();                          // vmcnt(0) drain (compiler)
#pragma unroll
        for (int sc = 0; sc < 2; ++sc) {
            const unsigned short* cA = lds + sc * 4096;
            const unsigned short* cB = lds + 8192 + sc * 4096;
            short8 af[4], bfr[4];
#pragma unroll
            for (int i = 0; i < 4; ++i)
                af[i]  = *(const short8*)(cA + (wm + i * 16 + r) * 32 + sw);
#pragma unroll
            for (int j = 0; j < 4; ++j)
                bfr[j] = *(const short8*)(cB + (wn + j * 16 + r) * 32 + sw);
            __builtin_amdgcn_s_setprio(1);
#pragma unroll
            for (int i = 0; i < 4; ++i)
#pragma unroll
                for (int j = 0; j < 4; ++j)
                    acc[i][j] = __builtin_amdgcn_mfma_f32_16x16x32_bf16(
                        af[i], bfr[j], acc[i][j], 0, 0, 0);
            __builtin_amdgcn_s_setprio(0);
        }
    }

    float* outb = mem + (size_t)b * H_ * H_;
#pragma unroll
    for (int i = 0; i < 4; ++i)
#pragma unroll
        for (int j = 0; j < 4; ++j)
#pragma unroll
            for (int d = 0; d < 4; ++d) {
                int row_l = wm + i * 16 + quad * 4 + d;
                int col_l = wn + j * 16 + r;
                outb[(size_t)(m0 + row_l) * H_ + n0 + col_l] = acc[i][j][d];
            }
}

extern "C" void kernel_launch(void* const* d_in, const int* in_sizes, int n_in,
                              void* d_out, int out_size, void* d_ws, size_t ws_size,
                              hipStream_t stream) {
    const float* x = (const float*)d_in[0];   // [16,1024,1024] f32
    const float* W = (const float*)d_in[1];   // [2048,1024] f32
    float* out = (float*)d_out;               // mem(16M) | keys(16M) | vals(16M) f32

    // Stash bf16 inputs in d_out's mem region (not written until gemm2)
    unsigned short* xb = (unsigned short*)d_out;            // 33.5 MB
    unsigned short* Wb = xb + (size_t)XN;                   //  4.2 MB (total 37.7 < 64 MB)

    // ws: keysT/valsT bf16 [B][H][S] (64 MB)
    unsigned short* kT = (unsigned short*)d_ws;
    unsigned short* vT = kT + (size_t)B_ * H_ * S_;

    convert_kernel<<<dim3((XN + WN) / 2048), dim3(256), 0, stream>>>(x, W, xb, Wb);

    gemm1_kernel<<<dim3(512), dim3(512), 0, stream>>>(xb, Wb, out, kT, vT);

    gemm2_kernel<<<dim3(1024), dim3(256), 0, stream>>>(kT, vT, out);
}

// Round 5
// 352.651 us; speedup vs baseline: 1.0869x; 1.0001x over previous
//
#include <hip/hip_runtime.h>

// Problem constants
#define B_  16
#define S_  1024
#define IN_ 1024
#define H_  1024
#define N1  (2*H_)          // 2048 output cols of GEMM1
#define M1  (B_*S_)         // 16384 rows of GEMM1
#define K1  IN_             // 1024
#define XN  (M1*IN_)        // 16,777,216 elems of x
#define WN  (N1*IN_)        //  2,097,152 elems of W

// Unified core: 256x256 tile, 8 waves, 32 phases of K=32, ring of 4 LDS slots
// (slot = A[256][32] + B[256][32] bf16 = 32 KiB), stage 3 phases ahead,
// frag ds_reads pipelined 1 phase ahead (F0/F1 named sets).
#define BM  256
#define BN  256
#define CP  257             // epilogue transpose LDS stride (odd -> conflict-free)
#define SLOT 16384          // shorts per ring slot (A 8192 + B 8192)

typedef __attribute__((ext_vector_type(8))) short  short8;   // 8 bf16 (MFMA A/B frag)
typedef __attribute__((ext_vector_type(4))) float  floatx4;  // MFMA C/D frag

// fp32 -> bf16 round-to-nearest-even
__device__ __forceinline__ unsigned short f2bf(float f) {
    unsigned int u = __float_as_uint(f);
    u += 0x7fffu + ((u >> 16) & 1u);
    return (unsigned short)(u >> 16);
}

// async global->LDS, 16 B per lane; LDS dst is wave-uniform base + lane*16
#define GLDS16(gp, lp) __builtin_amdgcn_global_load_lds(                      \
    (const __attribute__((address_space(1))) void*)(gp),                      \
    (__attribute__((address_space(3))) void*)(lp), 16, 0, 0)

#define WAITVM(N) { asm volatile("s_waitcnt vmcnt(" #N ")" ::: "memory");     \
                    __builtin_amdgcn_s_barrier();                             \
                    __builtin_amdgcn_sched_barrier(0); }

// ---------------------------------------------------------------------------
// convert: fp32 -> bf16 for x and W (memory-bound).
// ---------------------------------------------------------------------------
__global__ __launch_bounds__(256) void convert_kernel(
    const float* __restrict__ x, const float* __restrict__ W,
    unsigned short* __restrict__ xb, unsigned short* __restrict__ Wb)
{
    size_t i = ((size_t)blockIdx.x * 256 + threadIdx.x) * 8;
    const float* src;
    unsigned short* dst;
    if (i < (size_t)XN) { src = x + i; dst = xb + i; }
    else                { src = W + (i - XN); dst = Wb + (i - XN); }
    float4 a = *(const float4*)(src);
    float4 b = *(const float4*)(src + 4);
    ushort4 p = { f2bf(a.x), f2bf(a.y), f2bf(a.z), f2bf(a.w) };
    ushort4 q = { f2bf(b.x), f2bf(b.y), f2bf(b.z), f2bf(b.w) };
    *(ushort4*)(dst)     = p;
    *(ushort4*)(dst + 4) = q;
}

// ---------------------------------------------------------------------------
// Stage phase q (k-columns [q*32, q*32+32)) into ring slot q&3.
// Swizzle on GLOBAL source: phys chunk p at row holds logical c = p^(row&3);
// LDS dest linear (global_load_lds constraint). 4 glds/thread (2 A + 2 B).
// ---------------------------------------------------------------------------
__device__ __forceinline__ void stage_phase(
    const unsigned short* Ag, const unsigned short* Bg,
    unsigned short* lds, int q, int wave, int lane)
{
    unsigned short* slot = lds + (q & 3) * SLOT;
    const int kt = q * 32;
#pragma unroll
    for (int h = 0; h < 2; ++h) {
        int e   = (wave * 2 + h) * 64 + lane;     // chunk id 0..1023 in unit
        int row = e >> 2, p = e & 3;
        int c   = p ^ (row & 3);
        size_t go = (size_t)row * 1024 + kt + c * 8;
        GLDS16(Ag + go, slot + (wave * 2 + h) * 512);
        GLDS16(Bg + go, slot + 8192 + (wave * 2 + h) * 512);
    }
}

// ds_read the 12 b128 fragments (8 A + 4 B) of phase q into a named set.
// Reader slot = quad^(r&3): uniform 8 lanes per 16B slot -> b128 floor.
__device__ __forceinline__ void read_frags(
    const unsigned short* lds, int q, short8 (&fa)[8], short8 (&fb)[4],
    int wmw, int wnw, int r, int sw)
{
    const unsigned short* cA = lds + (q & 3) * SLOT;
    const unsigned short* cB = cA + 8192;
#pragma unroll
    for (int i = 0; i < 8; ++i)
        fa[i] = *(const short8*)(cA + (wmw + i * 16 + r) * 32 + sw);
#pragma unroll
    for (int j = 0; j < 4; ++j)
        fb[j] = *(const short8*)(cB + (wnw + j * 16 + r) * 32 + sw);
}

__device__ __forceinline__ void mfma32(
    floatx4 (&acc)[8][4], const short8 (&fa)[8], const short8 (&fb)[4])
{
    __builtin_amdgcn_s_setprio(1);
#pragma unroll
    for (int i = 0; i < 8; ++i)
#pragma unroll
        for (int j = 0; j < 4; ++j)
            acc[i][j] = __builtin_amdgcn_mfma_f32_16x16x32_bf16(
                fa[i], fb[j], acc[i][j], 0, 0, 0);
    __builtin_amdgcn_s_setprio(0);
}

// ---------------------------------------------------------------------------
// K-loop: 32 phases. Per phase p: [vmcnt(4)+barrier] -> read frags(p+1)
// (overlaps with MFMA below) -> stage(p+3) -> 32 MFMA on frags(p) (compiler
// emits counted lgkmcnt(12): frags(p) reads done, frags(p+1) in flight).
// vmcnt never drains to 0 in the main loop (T4); stage(q) has ~2 phases of
// latency cover before its ds_read.
// ---------------------------------------------------------------------------
__device__ __forceinline__ void gemm_core(
    const unsigned short* Ag, const unsigned short* Bg,
    unsigned short* lds, floatx4 (&acc)[8][4], int wave, int lane)
{
    const int quad = lane >> 4, r = lane & 15;
    const int wmw  = (wave >> 2) * 128;           // 2 wave-rows x 4 wave-cols
    const int wnw  = (wave & 3) * 64;
    const int sw   = (quad ^ (r & 3)) * 8;

    short8 F0a[8], F1a[8];
    short8 F0b[4], F1b[4];

    stage_phase(Ag, Bg, lds, 0, wave, lane);
    stage_phase(Ag, Bg, lds, 1, wave, lane);
    stage_phase(Ag, Bg, lds, 2, wave, lane);
    asm volatile("s_waitcnt vmcnt(8)" ::: "memory");   // stage(0) landed
    __builtin_amdgcn_s_barrier();
    __builtin_amdgcn_sched_barrier(0);
    read_frags(lds, 0, F0a, F0b, wmw, wnw, r, sw);

    for (int p = 0; p < 30; p += 2) {
        WAITVM(4)                                  // stage(p+1) landed
        read_frags(lds, p + 1, F1a, F1b, wmw, wnw, r, sw);
        stage_phase(Ag, Bg, lds, p + 3, wave, lane);
        mfma32(acc, F0a, F0b);
        WAITVM(4)                                  // stage(p+2) landed
        read_frags(lds, p + 2, F0a, F0b, wmw, wnw, r, sw);
        if (p + 4 < 32) stage_phase(Ag, Bg, lds, p + 4, wave, lane);
        mfma32(acc, F1a, F1b);
    }
    WAITVM(0)                                      // stage(31) landed
    read_frags(lds, 31, F1a, F1b, wmw, wnw, r, sw);
    mfma32(acc, F0a, F0b);                         // phase 30
    mfma32(acc, F1a, F1b);                         // phase 31
    __syncthreads();                               // LDS reusable by epilogue
}

// ---------------------------------------------------------------------------
// GEMM1: C[m,n] = sum_k xb[m,k]*Wb[n,k]; relu -> fp32 keys/vals to d_out and
// bf16 transposed keysT/valsT to ws. 512 blocks; XCD x owns m-stripe
// [8x,8x+8) x all 8 n-tiles.
// ---------------------------------------------------------------------------
__global__ __launch_bounds__(512, 2) void gemm1_kernel(
    const unsigned short* __restrict__ xb, const unsigned short* __restrict__ Wb,
    float* __restrict__ out,
    unsigned short* __restrict__ kT, unsigned short* __restrict__ vT)
{
    __shared__ unsigned short lds[65536];         // 128 KiB (4 ring slots)

    const int tid  = threadIdx.x;
    const int wave = tid >> 6, lane = tid & 63;
    const int quad = lane >> 4, r = lane & 15;
    const int wmw  = (wave >> 2) * 128;
    const int wnw  = (wave & 3) * 64;

    const int L   = blockIdx.x;
    const int xcd = L & 7, s = L >> 3;            // s: 0..63
    const int mt  = xcd * 8 + (s >> 3);           // 0..63
    const int nt  = s & 7;                        // 0..7
    const int m0  = mt * BM, n0 = nt * BN;

    const unsigned short* Ag = xb + (size_t)m0 * K1;
    const unsigned short* Bg = Wb + (size_t)n0 * K1;

    floatx4 acc[8][4] = {};
    gemm_core(Ag, Bg, lds, acc, wave, lane);

    const bool isKeys = (nt < 4);
    float* outKV    = out + (isKeys ? (size_t)M1 * H_ : (size_t)2 * M1 * H_);
    const int ncol0 = isKeys ? n0 : (n0 - 1024);

    // fp32 relu writes (each wave its own 128x64 region)
#pragma unroll
    for (int f = 0; f < 8; ++f)
#pragma unroll
        for (int j = 0; j < 4; ++j)
#pragma unroll
            for (int d = 0; d < 4; ++d) {
                int row_l = wmw + f * 16 + quad * 4 + d;
                int col_l = wnw + j * 16 + r;
                outKV[(size_t)(m0 + row_l) * H_ + ncol0 + col_l] =
                    fmaxf(acc[f][j][d], 0.0f);
            }

    // bf16 transposed writes via LDS, 2 chunks of 128 rows (CP=257)
    unsigned short* wsT = isKeys ? kT : vT;
    const int b  = m0 >> 10;
    const int s0 = m0 & 1023;
    unsigned short* dstB = wsT + (size_t)b * H_ * S_ + (size_t)ncol0 * S_ + s0;

#pragma unroll
    for (int ch = 0; ch < 2; ++ch) {
        if ((wave >> 2) == ch) {
#pragma unroll
            for (int f = 0; f < 8; ++f)
#pragma unroll
                for (int j = 0; j < 4; ++j)
#pragma unroll
                    for (int d = 0; d < 4; ++d) {
                        int lrow = f * 16 + quad * 4 + d;    // 0..127
                        int col  = wnw + j * 16 + r;         // 0..255
                        lds[lrow * CP + col] = f2bf(fmaxf(acc[f][j][d], 0.0f));
                    }
        }
        __syncthreads();
#pragma unroll
        for (int it = 0; it < 16; ++it) {
            int o   = it * 512 + tid;
            int n_l = o >> 5;                     // 0..255
            int m4  = (o & 31) * 4;               // 0..124
            ushort4 v;
            v.x = lds[(m4 + 0) * CP + n_l];
            v.y = lds[(m4 + 1) * CP + n_l];
            v.z = lds[(m4 + 2) * CP + n_l];
            v.w = lds[(m4 + 3) * CP + n_l];
            *(ushort4*)(dstB + (size_t)n_l * S_ + ch * 128 + m4) = v;
        }
        __syncthreads();
    }
}

// ---------------------------------------------------------------------------
// GEMM2 (batched): mem[b][m,n] = sum_t kT[b][m,t]*vT[b][n,t].
// Same pipelined core. 256 blocks (16 batches x 16 tiles of 256^2);
// XCD x owns batches {2x,2x+1}.
// ---------------------------------------------------------------------------
__global__ __launch_bounds__(512, 2) void gemm2_kernel(
    const unsigned short* __restrict__ kT, const unsigned short* __restrict__ vT,
    float* __restrict__ mem)
{
    __shared__ unsigned short lds[65536];         // 128 KiB (4 ring slots)

    const int tid  = threadIdx.x;
    const int wave = tid >> 6, lane = tid & 63;
    const int quad = lane >> 4, r = lane & 15;
    const int wmw  = (wave >> 2) * 128;
    const int wnw  = (wave & 3) * 64;

    const int L   = blockIdx.x;
    const int xcd = L & 7, s = L >> 3;            // s: 0..31
    const int b   = xcd * 2 + (s >> 4);           // batch 0..15
    const int tt  = s & 15;
    const int m0  = (tt >> 2) * BM;
    const int n0  = (tt & 3) * BN;

    const unsigned short* Ag = kT + (size_t)b * H_ * S_ + (size_t)m0 * S_;
    const unsigned short* Bg = vT + (size_t)b * H_ * S_ + (size_t)n0 * S_;

    floatx4 acc[8][4] = {};
    gemm_core(Ag, Bg, lds, acc, wave, lane);

    float* outb = mem + (size_t)b * H_ * H_;
#pragma unroll
    for (int f = 0; f < 8; ++f)
#pragma unroll
        for (int j = 0; j < 4; ++j)
#pragma unroll
            for (int d = 0; d < 4; ++d) {
                int row_l = wmw + f * 16 + quad * 4 + d;
                int col_l = wnw + j * 16 + r;
                outb[(size_t)(m0 + row_l) * H_ + n0 + col_l] = acc[f][j][d];
            }
}

extern "C" void kernel_launch(void* const* d_in, const int* in_sizes, int n_in,
                              void* d_out, int out_size, void* d_ws, size_t ws_size,
                              hipStream_t stream) {
    const float* x = (const float*)d_in[0];   // [16,1024,1024] f32
    const float* W = (const float*)d_in[1];   // [2048,1024] f32
    float* out = (float*)d_out;               // mem(16M) | keys(16M) | vals(16M) f32

    // Stash bf16 inputs in d_out's mem region (not written until gemm2)
    unsigned short* xb = (unsigned short*)d_out;            // 33.5 MB
    unsigned short* Wb = xb + (size_t)XN;                   //  4.2 MB (total 37.7 < 64 MB)

    // ws: keysT/valsT bf16 [B][H][S] (64 MB)
    unsigned short* kT = (unsigned short*)d_ws;
    unsigned short* vT = kT + (size_t)B_ * H_ * S_;

    convert_kernel<<<dim3((XN + WN) / 2048), dim3(256), 0, stream>>>(x, W, xb, Wb);

    gemm1_kernel<<<dim3(512), dim3(512), 0, stream>>>(xb, Wb, out, kT, vT);

    gemm2_kernel<<<dim3(256), dim3(512), 0, stream>>>(kT, vT, out);
}